// Round 1
// baseline (1637.578 us; speedup 1.0000x reference)
//
#include <hip/hip_runtime.h>
#include <hip/hip_bf16.h>
#include <cstdint>

#define T_DIM 336
#define H_DIM 64
#define K_DIM 4
#define F_DIM 720
#define BN_TOT 16384

// ---------------------------------------------------------------------------
// Kernel 1: per-(b,n) row — mu/sigma MLPs, softplus, weight-gen MLP, softmax.
// Writes spmu[BN][4], spsg[BN][4], w[BN][4] to workspace.
// ---------------------------------------------------------------------------
__global__ __launch_bounds__(256) void gen_stats_kernel(
    const float* __restrict__ x, const float* __restrict__ eps,
    const float* __restrict__ muW1, const float* __restrict__ mub1,
    const float* __restrict__ muW2, const float* __restrict__ mub2,
    const float* __restrict__ sgW1, const float* __restrict__ sgb1,
    const float* __restrict__ sgW2, const float* __restrict__ sgb2,
    const float* __restrict__ wgW1, const float* __restrict__ wgb1,
    const float* __restrict__ wgW2, const float* __restrict__ wgb2,
    float* __restrict__ spmu, float* __restrict__ spsg, float* __restrict__ wout)
{
  int bn = blockIdx.x;
  __shared__ float xs[T_DIM];
  __shared__ float h[128];              // mu hidden [0..63], sg hidden [64..127]
  __shared__ float zs[K_DIM * T_DIM];
  __shared__ float hw[K_DIM][H_DIM];
  __shared__ float sp[8];               // spmu[0..3], spsg[4..7]
  __shared__ float lg[4];
  int tid = threadIdx.x;

  const float* xp = x + (size_t)bn * T_DIM;
  for (int i = tid; i < T_DIM; i += 256) xs[i] = xp[i];
  __syncthreads();

  if (tid < 128) {
    int j = tid & 63;
    const float* W = (tid < 64) ? muW1 : sgW1;
    const float* B = (tid < 64) ? mub1 : sgb1;
    const float* Wr = W + (size_t)j * T_DIM;
    float a = 0.f;
    for (int t = 0; t < T_DIM; ++t) a = fmaf(xs[t], Wr[t], a);
    h[tid] = fmaxf(a + B[j], 0.f);
  }
  __syncthreads();

  if (tid < 8) {
    int kk = tid & 3;
    bool ismu = tid < 4;
    const float* W2 = ismu ? muW2 : sgW2;
    const float* B2 = ismu ? mub2 : sgb2;
    const float* hh = ismu ? h : (h + 64);
    float a = 0.f;
    for (int j = 0; j < H_DIM; ++j) a = fmaf(hh[j], W2[kk * H_DIM + j], a);
    a += B2[kk];
    // softplus, numerically stable: max(a,0) + log1p(exp(-|a|))
    float s = fmaxf(a, 0.f) + log1pf(expf(-fabsf(a)));
    sp[tid] = s;
    if (ismu) spmu[(size_t)bn * 4 + kk] = s;
    else      spsg[(size_t)bn * 4 + kk] = s;
  }
  __syncthreads();

  const float* ep = eps + (size_t)bn * (K_DIM * T_DIM);
  for (int i = tid; i < K_DIM * T_DIM; i += 256) {
    int kk = i / T_DIM;
    zs[i] = fmaf(ep[i], sp[4 + kk], sp[kk]);
  }
  __syncthreads();

  {
    int kk = tid >> 6, j = tid & 63;     // wave-uniform kk
    const float* Wr = wgW1 + (size_t)j * T_DIM;
    const float* zz = zs + kk * T_DIM;
    float a = 0.f;
    for (int t = 0; t < T_DIM; ++t) a = fmaf(zz[t], Wr[t], a);
    hw[kk][j] = fmaxf(a + wgb1[j], 0.f);
  }
  __syncthreads();

  if (tid < 4) {
    float a = 0.f;
    for (int j = 0; j < H_DIM; ++j) a = fmaf(hw[tid][j], wgW2[j], a);
    lg[tid] = a + wgb2[0];
  }
  __syncthreads();

  if (tid == 0) {
    float m = fmaxf(fmaxf(lg[0], lg[1]), fmaxf(lg[2], lg[3]));
    float e0 = expf(lg[0] - m), e1 = expf(lg[1] - m);
    float e2 = expf(lg[2] - m), e3 = expf(lg[3] - m);
    float inv = 1.f / (e0 + e1 + e2 + e3);
    float* wp = wout + (size_t)bn * 4;
    wp[0] = e0 * inv; wp[1] = e1 * inv; wp[2] = e2 * inv; wp[3] = e3 * inv;
  }
}

// ---------------------------------------------------------------------------
// Kernel 2: fused fitter GEMM. Per (row-tile of 32, k): hf = relu(Z @ W1^T + b1),
// coeffs = hf @ W2^T + b2 reduced in-register (never materializes hf).
// Z computed on the fly from eps + softplus scalars, fully LDS-resident.
// ---------------------------------------------------------------------------
#define BM 32
#define FT 128
#define BK 24

struct FitParams {
  const float* w1[4];
  const float* b1[4];
  const float* w2[4];
  const float* b2[4];
};

__global__ __launch_bounds__(256) void fitter_kernel(
    const float* __restrict__ eps, const float* __restrict__ spmu,
    const float* __restrict__ spsg, FitParams fp, float* __restrict__ coeffs)
{
  int k = blockIdx.y;
  int r0 = blockIdx.x * BM;
  const float* W1  = fp.w1[k];
  const float* B1  = fp.b1[k];
  const float* W2  = fp.w2[k];
  const float* B2  = fp.b2[k];
  int deg = (k == 1) ? 2 : (k == 2) ? 3 : 1;

  __shared__ float zt[T_DIM][BM];   // 336*32*4 = 43008 B, t-major for b128 reads
  __shared__ float w1t[BK][FT];     // 24*128*4 = 12288 B, t-major
  __shared__ float smu[BM], ssg[BM];
  __shared__ float cred[BM][3];

  int tid = threadIdx.x;
  if (tid < BM) {
    smu[tid] = spmu[(size_t)(r0 + tid) * 4 + k];
    ssg[tid] = spsg[(size_t)(r0 + tid) * 4 + k];
  }
  if (tid >= 64 && tid < 64 + BM * 3) {
    int q = tid - 64;
    cred[q / 3][q % 3] = 0.f;
  }
  __syncthreads();

  // stage z tile: z[r][t] = smu[r] + eps[r][k][t]*ssg[r], stored transposed
  for (int i = tid; i < BM * (T_DIM / 4); i += 256) {
    int r = i / 84, t4 = i - r * 84;
    const float4 e = ((const float4*)(eps + ((size_t)(r0 + r) * 4 + k) * T_DIM))[t4];
    float m = smu[r], s = ssg[r];
    int t = t4 * 4;
    zt[t][r]     = fmaf(e.x, s, m);
    zt[t + 1][r] = fmaf(e.y, s, m);
    zt[t + 2][r] = fmaf(e.z, s, m);
    zt[t + 3][r] = fmaf(e.w, s, m);
  }

  int tr = tid & 7;    // row group: rows tr*4 .. tr*4+3
  int tf = tid >> 3;   // f group:   f = f0 + tf*4 .. +3
  float cpart[4][3] = {{0.f}};

  for (int f0 = 0; f0 < 768; f0 += FT) {
    float acc[4][4] = {{0.f}};
    for (int t0 = 0; t0 < T_DIM; t0 += BK) {
      __syncthreads();   // protects zt (first iter) and previous w1t readers
      // stage W1 tile transposed: w1t[t][f]
      for (int i = tid; i < FT * (BK / 4); i += 256) {   // 128*6 = 768
        int ff = i / 6, t4 = i - ff * 6;
        int f = f0 + ff;
        float4 v = make_float4(0.f, 0.f, 0.f, 0.f);
        if (f < F_DIM) v = ((const float4*)(W1 + (size_t)f * T_DIM + t0))[t4];
        int tt = t4 * 4;
        w1t[tt][ff]     = v.x;
        w1t[tt + 1][ff] = v.y;
        w1t[tt + 2][ff] = v.z;
        w1t[tt + 3][ff] = v.w;
      }
      __syncthreads();
      #pragma unroll
      for (int t = 0; t < BK; ++t) {
        const float4 zv = *(const float4*)&zt[t0 + t][tr * 4];
        const float4 wv = *(const float4*)&w1t[t][tf * 4];
        acc[0][0] = fmaf(zv.x, wv.x, acc[0][0]);
        acc[0][1] = fmaf(zv.x, wv.y, acc[0][1]);
        acc[0][2] = fmaf(zv.x, wv.z, acc[0][2]);
        acc[0][3] = fmaf(zv.x, wv.w, acc[0][3]);
        acc[1][0] = fmaf(zv.y, wv.x, acc[1][0]);
        acc[1][1] = fmaf(zv.y, wv.y, acc[1][1]);
        acc[1][2] = fmaf(zv.y, wv.z, acc[1][2]);
        acc[1][3] = fmaf(zv.y, wv.w, acc[1][3]);
        acc[2][0] = fmaf(zv.z, wv.x, acc[2][0]);
        acc[2][1] = fmaf(zv.z, wv.y, acc[2][1]);
        acc[2][2] = fmaf(zv.z, wv.z, acc[2][2]);
        acc[2][3] = fmaf(zv.z, wv.w, acc[2][3]);
        acc[3][0] = fmaf(zv.w, wv.x, acc[3][0]);
        acc[3][1] = fmaf(zv.w, wv.y, acc[3][1]);
        acc[3][2] = fmaf(zv.w, wv.z, acc[3][2]);
        acc[3][3] = fmaf(zv.w, wv.w, acc[3][3]);
      }
    }
    // fused epilogue: relu + W2 reduction into per-thread coeff partials
    #pragma unroll
    for (int jf = 0; jf < 4; ++jf) {
      int f = f0 + tf * 4 + jf;
      bool valid = (f < F_DIM);
      float bb  = valid ? B1[f] : 0.f;
      float w2a = valid ? W2[f] : 0.f;
      float w2b = (valid && deg > 1) ? W2[F_DIM + f] : 0.f;
      float w2c = (valid && deg > 2) ? W2[2 * F_DIM + f] : 0.f;
      #pragma unroll
      for (int jr = 0; jr < 4; ++jr) {
        float hv = fmaxf(acc[jr][jf] + bb, 0.f);
        cpart[jr][0] = fmaf(hv, w2a, cpart[jr][0]);
        cpart[jr][1] = fmaf(hv, w2b, cpart[jr][1]);
        cpart[jr][2] = fmaf(hv, w2c, cpart[jr][2]);
      }
    }
  }

  __syncthreads();
  #pragma unroll
  for (int jr = 0; jr < 4; ++jr) {
    atomicAdd(&cred[tr * 4 + jr][0], cpart[jr][0]);
    atomicAdd(&cred[tr * 4 + jr][1], cpart[jr][1]);
    atomicAdd(&cred[tr * 4 + jr][2], cpart[jr][2]);
  }
  __syncthreads();
  if (tid < BM * 3) {
    int r = tid / 3, j = tid - r * 3;
    float bias = (j < deg) ? B2[j] : 0.f;
    coeffs[(size_t)(r0 + r) * 12 + k * 3 + j] = cred[r][j] + bias;
  }
}

// ---------------------------------------------------------------------------
// Kernel 3: combine mixture weights + coeffs into cubic P0..P3, evaluate at
// t_f = f/719, write out[b][f][n] coalesced over n.
// ---------------------------------------------------------------------------
__global__ __launch_bounds__(256) void combine_kernel(
    const float* __restrict__ coeffs, const float* __restrict__ wsm,
    float* __restrict__ out)
{
  int b = blockIdx.x;
  int fc = blockIdx.y;
  __shared__ float P[4][128];
  int tid = threadIdx.x;
  if (tid < 128) {
    size_t bn = (size_t)b * 128 + tid;
    const float* c = coeffs + bn * 12;
    const float* w = wsm + bn * 4;
    float w0 = w[0], w1 = w[1], w2 = w[2], w3 = w[3];
    // degrees [1,2,3,1], signs [+.5,+.5,+.5,-.5]
    P[0][tid] = w0 * c[0] + w1 * c[3] + w2 * c[6] + w3 * c[9];
    P[1][tid] = w1 * c[4] + w2 * c[7] + 0.5f * (w0 - w3);
    P[2][tid] = w2 * c[8] + 0.5f * w1;
    P[3][tid] = 0.5f * w2;
  }
  __syncthreads();
  int n = tid & 127, fo = tid >> 7;
  float p0 = P[0][n], p1 = P[1][n], p2 = P[2][n], p3 = P[3][n];
  float* ob = out + (size_t)b * F_DIM * 128 + n;
  for (int f = fc * 120 + fo; f < fc * 120 + 120; f += 2) {
    float t = (float)f * (1.0f / 719.0f);
    ob[(size_t)f * 128] = fmaf(fmaf(fmaf(p3, t, p2), t, p1), t, p0);
  }
}

// ---------------------------------------------------------------------------
extern "C" void kernel_launch(void* const* d_in, const int* in_sizes, int n_in,
                              void* d_out, int out_size, void* d_ws, size_t ws_size,
                              hipStream_t stream) {
  const float* x    = (const float*)d_in[0];
  const float* eps  = (const float*)d_in[1];
  const float* muW1 = (const float*)d_in[2];
  const float* mub1 = (const float*)d_in[3];
  const float* muW2 = (const float*)d_in[4];
  const float* mub2 = (const float*)d_in[5];
  const float* sgW1 = (const float*)d_in[6];
  const float* sgb1 = (const float*)d_in[7];
  const float* sgW2 = (const float*)d_in[8];
  const float* sgb2 = (const float*)d_in[9];
  const float* wgW1 = (const float*)d_in[10];
  const float* wgb1 = (const float*)d_in[11];
  const float* wgW2 = (const float*)d_in[12];
  const float* wgb2 = (const float*)d_in[13];

  float* ws     = (float*)d_ws;
  float* spmu   = ws;                 // 16384*4
  float* spsg   = ws + 65536;         // 16384*4
  float* wsm    = ws + 131072;        // 16384*4
  float* coeffs = ws + 196608;        // 16384*12

  gen_stats_kernel<<<BN_TOT, 256, 0, stream>>>(
      x, eps, muW1, mub1, muW2, mub2, sgW1, sgb1, sgW2, sgb2,
      wgW1, wgb1, wgW2, wgb2, spmu, spsg, wsm);

  FitParams fp;
  for (int i = 0; i < 4; ++i) {
    fp.w1[i] = (const float*)d_in[14 + 4 * i];
    fp.b1[i] = (const float*)d_in[15 + 4 * i];
    fp.w2[i] = (const float*)d_in[16 + 4 * i];
    fp.b2[i] = (const float*)d_in[17 + 4 * i];
  }
  fitter_kernel<<<dim3(BN_TOT / BM, 4), 256, 0, stream>>>(eps, spmu, spsg, fp, coeffs);

  combine_kernel<<<dim3(128, 6), 256, 0, stream>>>(coeffs, wsm, (float*)d_out);
}

// Round 2
// 577.248 us; speedup vs baseline: 2.8369x; 2.8369x over previous
//
#include <hip/hip_runtime.h>
#include <hip/hip_bf16.h>
#include <cstdint>

#define T_DIM 336
#define F_DIM 720
#define BN_TOT 16384
#define FT_LDK 360          // padded K stride (bf16 elems): 352 MFMA-K + 8 pad
#define FT_BM 64
#define FT_KS 11            // 11 K-steps of 32 = 352

typedef float  f32x4 __attribute__((ext_vector_type(4)));
typedef short  s16x8 __attribute__((ext_vector_type(8)));

struct FitParams {
  const float* w1[4];
  const float* b1[4];
  const float* w2[4];
  const float* b2[4];
};

__device__ __forceinline__ unsigned short f2bf(float x) {
  union { float f; unsigned u; } v; v.f = x;
  unsigned r = v.u + 0x7FFFu + ((v.u >> 16) & 1u);   // RNE
  return (unsigned short)(r >> 16);
}

// ---------------------------------------------------------------------------
// Kernel 0: convert W1[k] fp32 [720][336] -> bf16 padded [768][360], zeros pad.
// ---------------------------------------------------------------------------
__global__ __launch_bounds__(256) void wconv_kernel(FitParams fp,
                                                    unsigned short* __restrict__ w1g)
{
  int idx = blockIdx.x * 256 + threadIdx.x;       // one thread per 4 shorts
  if (idx >= 4 * 768 * 90) return;                // 4*768*360/4
  int s = idx * 4;
  int k = s / (768 * 360);
  int rem = s - k * (768 * 360);
  int f = rem / 360;
  int t = rem - f * 360;
  const float* W = fp.w1[k];
  ushort4 o;
  o.x = (f < F_DIM && t     < T_DIM) ? f2bf(W[(size_t)f * T_DIM + t    ]) : 0;
  o.y = (f < F_DIM && t + 1 < T_DIM) ? f2bf(W[(size_t)f * T_DIM + t + 1]) : 0;
  o.z = (f < F_DIM && t + 2 < T_DIM) ? f2bf(W[(size_t)f * T_DIM + t + 2]) : 0;
  o.w = (f < F_DIM && t + 3 < T_DIM) ? f2bf(W[(size_t)f * T_DIM + t + 3]) : 0;
  *(ushort4*)&w1g[s] = o;
}

// ---------------------------------------------------------------------------
// Kernel A: mu/sigma MLPs. Tiled fp32 GEMM [16384 x 336] x [336 x 128](concat)
// -> relu -> second layer (128 -> 8) -> softplus -> spmu/spsg.
// ---------------------------------------------------------------------------
__global__ __launch_bounds__(256) void musig_kernel(
    const float* __restrict__ x,
    const float* __restrict__ muW1, const float* __restrict__ mub1,
    const float* __restrict__ muW2, const float* __restrict__ mub2,
    const float* __restrict__ sgW1, const float* __restrict__ sgb1,
    const float* __restrict__ sgW2, const float* __restrict__ sgb2,
    float* __restrict__ spmu, float* __restrict__ spsg)
{
  int r0 = blockIdx.x * 32;
  __shared__ __align__(16) float xt[T_DIM][32];
  __shared__ __align__(16) float w1t[24][128];
  __shared__ float h[32][132];
  __shared__ float w2s[8][66];
  int tid = threadIdx.x;

  {  // stage x transposed: lane-major over rows -> consecutive banks
    int r = tid & 31;
    const float* xp = x + (size_t)(r0 + r) * T_DIM;
    for (int c = (tid >> 5); c < 84; c += 8) {
      float4 v = ((const float4*)xp)[c];
      int t = c * 4;
      xt[t][r] = v.x; xt[t+1][r] = v.y; xt[t+2][r] = v.z; xt[t+3][r] = v.w;
    }
  }
  {  // stage second-layer weights
    int o = tid >> 5, j = tid & 31;
    w2s[o][j]      = (o < 4) ? muW2[o * 64 + j]      : sgW2[(o - 4) * 64 + j];
    w2s[o][j + 32] = (o < 4) ? muW2[o * 64 + j + 32] : sgW2[(o - 4) * 64 + j + 32];
  }

  int tr = tid & 7, tf = tid >> 3;
  float acc[4][4] = {};
  for (int t0 = 0; t0 < T_DIM; t0 += 24) {
    __syncthreads();
    {  // stage W1 tile transposed, lane-major over cols
      int ff = tid & 127;
      const float* Wr = (ff < 64) ? (muW1 + (size_t)ff * T_DIM)
                                  : (sgW1 + (size_t)(ff - 64) * T_DIM);
      for (int c2 = tid >> 7; c2 < 6; c2 += 2) {
        float4 v = ((const float4*)(Wr + t0))[c2];
        int tt = c2 * 4;
        w1t[tt][ff] = v.x; w1t[tt+1][ff] = v.y; w1t[tt+2][ff] = v.z; w1t[tt+3][ff] = v.w;
      }
    }
    __syncthreads();
    #pragma unroll
    for (int t = 0; t < 24; ++t) {
      float4 zv = *(const float4*)&xt[t0 + t][tr * 4];
      float4 wv = *(const float4*)&w1t[t][tf * 4];
      acc[0][0] = fmaf(zv.x, wv.x, acc[0][0]); acc[0][1] = fmaf(zv.x, wv.y, acc[0][1]);
      acc[0][2] = fmaf(zv.x, wv.z, acc[0][2]); acc[0][3] = fmaf(zv.x, wv.w, acc[0][3]);
      acc[1][0] = fmaf(zv.y, wv.x, acc[1][0]); acc[1][1] = fmaf(zv.y, wv.y, acc[1][1]);
      acc[1][2] = fmaf(zv.y, wv.z, acc[1][2]); acc[1][3] = fmaf(zv.y, wv.w, acc[1][3]);
      acc[2][0] = fmaf(zv.z, wv.x, acc[2][0]); acc[2][1] = fmaf(zv.z, wv.y, acc[2][1]);
      acc[2][2] = fmaf(zv.z, wv.z, acc[2][2]); acc[2][3] = fmaf(zv.z, wv.w, acc[2][3]);
      acc[3][0] = fmaf(zv.w, wv.x, acc[3][0]); acc[3][1] = fmaf(zv.w, wv.y, acc[3][1]);
      acc[3][2] = fmaf(zv.w, wv.z, acc[3][2]); acc[3][3] = fmaf(zv.w, wv.w, acc[3][3]);
    }
  }
  #pragma unroll
  for (int jr = 0; jr < 4; ++jr)
    #pragma unroll
    for (int jc = 0; jc < 4; ++jc) {
      int j = tf * 4 + jc;
      float b = (j < 64) ? mub1[j] : sgb1[j - 64];
      h[tr * 4 + jr][j] = fmaxf(acc[jr][jc] + b, 0.f);
    }
  __syncthreads();
  {
    int r = tid >> 3, o = tid & 7;
    const float* hb = &h[r][(o < 4) ? 0 : 64];
    float a = 0.f;
    #pragma unroll 16
    for (int j = 0; j < 64; ++j) a = fmaf(hb[j], w2s[o][j], a);
    a += (o < 4) ? mub2[o] : sgb2[o - 4];
    float sp = fmaxf(a, 0.f) + log1pf(expf(-fabsf(a)));
    if (o < 4) spmu[(size_t)(r0 + r) * 4 + o] = sp;
    else       spsg[(size_t)(r0 + r) * 4 + (o - 4)] = sp;
  }
}

// ---------------------------------------------------------------------------
// Kernel W: weight-gen MLP + softmax. Rows are flat (bn*4+k) = eps row index.
// GEMM [65536 x 336] x [336 x 64] -> relu -> dot(wgW2) -> softmax over k.
// ---------------------------------------------------------------------------
__global__ __launch_bounds__(256) void wg_kernel(
    const float* __restrict__ eps, const float* __restrict__ spmu,
    const float* __restrict__ spsg,
    const float* __restrict__ wgW1, const float* __restrict__ wgb1,
    const float* __restrict__ wgW2, const float* __restrict__ wgb2,
    float* __restrict__ wout)
{
  int r0 = blockIdx.x * 32;   // flat row = bn*4 + k
  __shared__ __align__(16) float zt[T_DIM][32];
  __shared__ __align__(16) float w1t[24][64];
  __shared__ float h[32][66];
  __shared__ float w2g[64];
  __shared__ float lgs[32];
  int tid = threadIdx.x;
  if (tid < 64) w2g[tid] = wgW2[tid];

  {  // stage z = spmu + eps * spsg, transposed
    int r = tid & 31;
    float m = spmu[r0 + r], s = spsg[r0 + r];
    const float* ep = eps + (size_t)(r0 + r) * T_DIM;
    for (int c = (tid >> 5); c < 84; c += 8) {
      float4 v = ((const float4*)ep)[c];
      int t = c * 4;
      zt[t][r]   = fmaf(v.x, s, m);
      zt[t+1][r] = fmaf(v.y, s, m);
      zt[t+2][r] = fmaf(v.z, s, m);
      zt[t+3][r] = fmaf(v.w, s, m);
    }
  }

  int tr = tid & 7, tf = tid >> 3;
  float acc[4][2] = {};
  for (int t0 = 0; t0 < T_DIM; t0 += 24) {
    __syncthreads();
    {
      int ff = tid & 63;
      const float* Wr = wgW1 + (size_t)ff * T_DIM + t0;
      for (int c2 = tid >> 6; c2 < 6; c2 += 4) {
        float4 v = ((const float4*)Wr)[c2];
        int tt = c2 * 4;
        w1t[tt][ff] = v.x; w1t[tt+1][ff] = v.y; w1t[tt+2][ff] = v.z; w1t[tt+3][ff] = v.w;
      }
    }
    __syncthreads();
    #pragma unroll
    for (int t = 0; t < 24; ++t) {
      float4 zv = *(const float4*)&zt[t0 + t][tr * 4];
      float2 wv = *(const float2*)&w1t[t][tf * 2];
      acc[0][0] = fmaf(zv.x, wv.x, acc[0][0]); acc[0][1] = fmaf(zv.x, wv.y, acc[0][1]);
      acc[1][0] = fmaf(zv.y, wv.x, acc[1][0]); acc[1][1] = fmaf(zv.y, wv.y, acc[1][1]);
      acc[2][0] = fmaf(zv.z, wv.x, acc[2][0]); acc[2][1] = fmaf(zv.z, wv.y, acc[2][1]);
      acc[3][0] = fmaf(zv.w, wv.x, acc[3][0]); acc[3][1] = fmaf(zv.w, wv.y, acc[3][1]);
    }
  }
  {
    int j0 = tf * 2;
    #pragma unroll
    for (int jr = 0; jr < 4; ++jr) {
      h[tr * 4 + jr][j0]     = fmaxf(acc[jr][0] + wgb1[j0],     0.f);
      h[tr * 4 + jr][j0 + 1] = fmaxf(acc[jr][1] + wgb1[j0 + 1], 0.f);
    }
  }
  __syncthreads();
  {
    int r = tid >> 3, jg = tid & 7;
    float a = 0.f;
    #pragma unroll
    for (int jj = 0; jj < 8; ++jj) {
      int j = jg * 8 + jj;
      a = fmaf(h[r][j], w2g[j], a);
    }
    a += __shfl_xor(a, 1); a += __shfl_xor(a, 2); a += __shfl_xor(a, 4);
    if (jg == 0) lgs[r] = a + wgb2[0];
  }
  __syncthreads();
  if (tid < 8) {
    const float* l = &lgs[tid * 4];
    float m = fmaxf(fmaxf(l[0], l[1]), fmaxf(l[2], l[3]));
    float e0 = expf(l[0] - m), e1 = expf(l[1] - m);
    float e2 = expf(l[2] - m), e3 = expf(l[3] - m);
    float inv = 1.f / (e0 + e1 + e2 + e3);
    float* wp = wout + ((size_t)(r0 >> 2) + tid) * 4;
    wp[0] = e0 * inv; wp[1] = e1 * inv; wp[2] = e2 * inv; wp[3] = e3 * inv;
  }
}

// ---------------------------------------------------------------------------
// Kernel F: bf16 MFMA fitter. Per (64-row block, k): for each 64-f tile,
// C = Z @ W1^T via mfma_f32_16x16x32_bf16; relu + W2 reduction fused in regs;
// shfl-reduce over f-lanes -> LDS atomics -> coeffs.
// A: lane holds z[row = l&15][k-chunk (l>>4)*8 + 0..7]
// B: lane holds W1[f  = l&15][same k-chunk]        (B^T pattern)
// C: col(f) = l&15, row(r) = (l>>4)*4 + reg        [guide §3, m89/m91]
// ---------------------------------------------------------------------------
__global__ __launch_bounds__(256, 1) void fitter_mfma_kernel(
    const float* __restrict__ eps, const float* __restrict__ spmu,
    const float* __restrict__ spsg, const unsigned short* __restrict__ w1g,
    FitParams fp, float* __restrict__ coeffs)
{
  int k = blockIdx.y;
  int r0 = blockIdx.x * FT_BM;
  const float* B1 = fp.b1[k];
  const float* W2 = fp.w2[k];
  const float* B2 = fp.b2[k];
  int deg = (k == 1) ? 2 : (k == 2) ? 3 : 1;

  __shared__ __align__(16) unsigned short sZ[FT_BM * FT_LDK];   // 46080 B
  __shared__ __align__(16) unsigned short sW[64 * FT_LDK];      // 46080 B
  __shared__ float cred[FT_BM][3];
  __shared__ float s_mu[FT_BM], s_sg[FT_BM];

  int tid = threadIdx.x;
  if (tid < FT_BM) {
    s_mu[tid] = spmu[(size_t)(r0 + tid) * 4 + k];
    s_sg[tid] = spsg[(size_t)(r0 + tid) * 4 + k];
  }
  if (tid < FT_BM * 3) cred[tid / 3][tid % 3] = 0.f;
  __syncthreads();

  // stage z tile as bf16 (row-major, padded stride 360; t>=336 zeros)
  {
    int r = tid & 63;
    float m = s_mu[r], s = s_sg[r];
    const float* ep = eps + ((size_t)(r0 + r) * 4 + k) * T_DIM;
    for (int c = (tid >> 6); c < 45; c += 4) {
      s16x8 o = {0, 0, 0, 0, 0, 0, 0, 0};
      if (c < 42) {
        float4 e0 = ((const float4*)ep)[c * 2];
        float4 e1 = ((const float4*)ep)[c * 2 + 1];
        o[0] = (short)f2bf(fmaf(e0.x, s, m));
        o[1] = (short)f2bf(fmaf(e0.y, s, m));
        o[2] = (short)f2bf(fmaf(e0.z, s, m));
        o[3] = (short)f2bf(fmaf(e0.w, s, m));
        o[4] = (short)f2bf(fmaf(e1.x, s, m));
        o[5] = (short)f2bf(fmaf(e1.y, s, m));
        o[6] = (short)f2bf(fmaf(e1.z, s, m));
        o[7] = (short)f2bf(fmaf(e1.w, s, m));
      }
      *(s16x8*)&sZ[r * FT_LDK + c * 8] = o;
    }
  }

  int lane = tid & 63;
  int wv = tid >> 6;
  int wr = wv >> 1, wc = wv & 1;
  int l15 = lane & 15, lgr = lane >> 4;

  float cpart[2][4][3] = {};
  const unsigned short* wsrc = w1g + (size_t)k * 768 * FT_LDK;
  const f32x4 zero4 = {0.f, 0.f, 0.f, 0.f};

  for (int ft = 0; ft < 12; ++ft) {
    __syncthreads();   // prior K-loop readers of sW done; sZ ready on first iter
    {  // stage W1 f-tile: pure linear copy (global layout == LDS layout)
      const unsigned short* g = wsrc + (size_t)ft * 64 * FT_LDK;
      for (int i = tid; i < 2880; i += 256) {
        s16x8 v = *(const s16x8*)(g + i * 8);
        *(s16x8*)&sW[i * 8] = v;
      }
    }
    __syncthreads();

    f32x4 acc00 = zero4, acc01 = zero4, acc10 = zero4, acc11 = zero4;
    #pragma unroll
    for (int s = 0; s < FT_KS; ++s) {
      int to = s * 32 + lgr * 8;
      s16x8 a0 = *(const s16x8*)&sZ[(wr * 32 + l15)      * FT_LDK + to];
      s16x8 a1 = *(const s16x8*)&sZ[(wr * 32 + 16 + l15) * FT_LDK + to];
      s16x8 b0 = *(const s16x8*)&sW[(wc * 32 + l15)      * FT_LDK + to];
      s16x8 b1 = *(const s16x8*)&sW[(wc * 32 + 16 + l15) * FT_LDK + to];
      acc00 = __builtin_amdgcn_mfma_f32_16x16x32_bf16(a0, b0, acc00, 0, 0, 0);
      acc01 = __builtin_amdgcn_mfma_f32_16x16x32_bf16(a0, b1, acc01, 0, 0, 0);
      acc10 = __builtin_amdgcn_mfma_f32_16x16x32_bf16(a1, b0, acc10, 0, 0, 0);
      acc11 = __builtin_amdgcn_mfma_f32_16x16x32_bf16(a1, b1, acc11, 0, 0, 0);
    }

    // fused epilogue: relu + W2 reduction into per-thread partials
    #pragma unroll
    for (int ni = 0; ni < 2; ++ni) {
      int f = ft * 64 + wc * 32 + ni * 16 + l15;
      bool valid = (f < F_DIM);
      float b1v = valid ? B1[f] : 0.f;
      float w2a = valid ? W2[f] : 0.f;
      float w2b = (valid && deg > 1) ? W2[F_DIM + f] : 0.f;
      float w2c = (valid && deg > 2) ? W2[2 * F_DIM + f] : 0.f;
      #pragma unroll
      for (int mi = 0; mi < 2; ++mi) {
        const f32x4 av = (ni == 0) ? (mi == 0 ? acc00 : acc10)
                                   : (mi == 0 ? acc01 : acc11);
        #pragma unroll
        for (int j = 0; j < 4; ++j) {
          float hv = fmaxf(av[j] + b1v, 0.f);
          cpart[mi][j][0] = fmaf(hv, w2a, cpart[mi][j][0]);
          cpart[mi][j][1] = fmaf(hv, w2b, cpart[mi][j][1]);
          cpart[mi][j][2] = fmaf(hv, w2c, cpart[mi][j][2]);
        }
      }
    }
  }

  // reduce over the 16 f-lanes (lane bits 0..3), then cross-wave via LDS atomics
  #pragma unroll
  for (int mi = 0; mi < 2; ++mi)
    #pragma unroll
    for (int j = 0; j < 4; ++j)
      #pragma unroll
      for (int d = 0; d < 3; ++d) {
        float v = cpart[mi][j][d];
        v += __shfl_xor(v, 1); v += __shfl_xor(v, 2);
        v += __shfl_xor(v, 4); v += __shfl_xor(v, 8);
        if (l15 == 0) atomicAdd(&cred[wr * 32 + mi * 16 + lgr * 4 + j][d], v);
      }
  __syncthreads();
  if (tid < FT_BM * 3) {
    int r = tid / 3, j = tid % 3;
    float bias = (j < deg) ? B2[j] : 0.f;
    coeffs[(size_t)(r0 + r) * 12 + k * 3 + j] = cred[r][j] + bias;
  }
}

// ---------------------------------------------------------------------------
// Kernel C: combine mixture weights + coeffs into cubic, evaluate, write [B,F,N].
// ---------------------------------------------------------------------------
__global__ __launch_bounds__(256) void combine_kernel(
    const float* __restrict__ coeffs, const float* __restrict__ wsm,
    float* __restrict__ out)
{
  int b = blockIdx.x;
  int fc = blockIdx.y;
  __shared__ float P[4][128];
  int tid = threadIdx.x;
  if (tid < 128) {
    size_t bn = (size_t)b * 128 + tid;
    const float* c = coeffs + bn * 12;
    const float* w = wsm + bn * 4;
    float w0 = w[0], w1 = w[1], w2 = w[2], w3 = w[3];
    // degrees [1,2,3,1], signs [+.5,+.5,+.5,-.5]
    P[0][tid] = w0 * c[0] + w1 * c[3] + w2 * c[6] + w3 * c[9];
    P[1][tid] = w1 * c[4] + w2 * c[7] + 0.5f * (w0 - w3);
    P[2][tid] = w2 * c[8] + 0.5f * w1;
    P[3][tid] = 0.5f * w2;
  }
  __syncthreads();
  int n = tid & 127, fo = tid >> 7;
  float p0 = P[0][n], p1 = P[1][n], p2 = P[2][n], p3 = P[3][n];
  float* ob = out + (size_t)b * F_DIM * 128 + n;
  for (int f = fc * 120 + fo; f < fc * 120 + 120; f += 2) {
    float t = (float)f * (1.0f / 719.0f);
    ob[(size_t)f * 128] = fmaf(fmaf(fmaf(p3, t, p2), t, p1), t, p0);
  }
}

// ---------------------------------------------------------------------------
extern "C" void kernel_launch(void* const* d_in, const int* in_sizes, int n_in,
                              void* d_out, int out_size, void* d_ws, size_t ws_size,
                              hipStream_t stream) {
  const float* x    = (const float*)d_in[0];
  const float* eps  = (const float*)d_in[1];
  const float* muW1 = (const float*)d_in[2];
  const float* mub1 = (const float*)d_in[3];
  const float* muW2 = (const float*)d_in[4];
  const float* mub2 = (const float*)d_in[5];
  const float* sgW1 = (const float*)d_in[6];
  const float* sgb1 = (const float*)d_in[7];
  const float* sgW2 = (const float*)d_in[8];
  const float* sgb2 = (const float*)d_in[9];
  const float* wgW1 = (const float*)d_in[10];
  const float* wgb1 = (const float*)d_in[11];
  const float* wgW2 = (const float*)d_in[12];
  const float* wgb2 = (const float*)d_in[13];

  float* ws     = (float*)d_ws;
  float* spmu   = ws;                              // 65536 floats
  float* spsg   = ws + 65536;
  float* wsm    = ws + 131072;
  float* coeffs = ws + 196608;                     // 196608 floats
  unsigned short* w1g = (unsigned short*)(ws + 393216);  // 4*768*360 bf16

  FitParams fp;
  for (int i = 0; i < 4; ++i) {
    fp.w1[i] = (const float*)d_in[14 + 4 * i];
    fp.b1[i] = (const float*)d_in[15 + 4 * i];
    fp.w2[i] = (const float*)d_in[16 + 4 * i];
    fp.b2[i] = (const float*)d_in[17 + 4 * i];
  }

  wconv_kernel<<<1080, 256, 0, stream>>>(fp, w1g);
  musig_kernel<<<BN_TOT / 32, 256, 0, stream>>>(
      x, muW1, mub1, muW2, mub2, sgW1, sgb1, sgW2, sgb2, spmu, spsg);
  wg_kernel<<<(BN_TOT * 4) / 32, 256, 0, stream>>>(
      eps, spmu, spsg, wgW1, wgb1, wgW2, wgb2, wsm);
  fitter_mfma_kernel<<<dim3(BN_TOT / FT_BM, 4), 256, 0, stream>>>(
      eps, spmu, spsg, w1g, fp, coeffs);
  combine_kernel<<<dim3(128, 6), 256, 0, stream>>>(coeffs, wsm, (float*)d_out);
}

// Round 3
// 349.511 us; speedup vs baseline: 4.6853x; 1.6516x over previous
//
#include <hip/hip_runtime.h>
#include <hip/hip_bf16.h>
#include <cstdint>

#define T_DIM 336
#define F_DIM 720
#define BN_TOT 16384

#define FT_BM   128          // rows per fitter block (4 row-groups of 32)
#define FT_S    22           // K-steps of 16 (352 padded K)
#define FT_NIT  23           // 32-wide f half-tiles per k (23*32 = 736 >= 720)
#define WG_T0   (4 * FT_NIT) // wg tiles start at tile 92 (2 tiles: hidden 0..63)
#define TILE_SH (FT_S * 64 * 8)   // shorts per tile = 11264 (22528 B)

typedef float  f32x16 __attribute__((ext_vector_type(16)));
typedef short  s16x8  __attribute__((ext_vector_type(8)));

struct FitParams {
  const float* w1[4];
  const float* b1[4];
  const float* w2[4];
  const float* b2[4];
};

__device__ __forceinline__ unsigned short f2bf(float x) {
  union { float f; unsigned u; } v; v.f = x;
  unsigned r = v.u + 0x7FFFu + ((v.u >> 16) & 1u);   // RNE
  return (unsigned short)(r >> 16);
}

__device__ __forceinline__ void gl_lds16(const void* g, void* l) {
  __builtin_amdgcn_global_load_lds(
      (const __attribute__((address_space(1))) void*)g,
      (__attribute__((address_space(3))) void*)l, 16, 0, 0);
}

// ---------------------------------------------------------------------------
// Kernel 0: pack W1[k] (fp32 [720][336]) and wgW1 ([64][336]) into bf16
// MFMA-fragment order: w1g[((tg*22 + s)*64 + lane)*8 + j] where for tile tg
// f = (tg%23)*32 + (lane&31), t = s*16 + (lane>>5)*8 + j.  B-frag layout of
// v_mfma_f32_32x32x16_bf16 (lane: col=l&31, k-half=l>>5)  => staging into LDS
// is a pure linear copy and every ds_read_b128 is lane-linear (conflict-free).
// ---------------------------------------------------------------------------
__global__ __launch_bounds__(256) void wconv_kernel(FitParams fp,
    const float* __restrict__ wgW1, unsigned short* __restrict__ w1g)
{
  int idx = blockIdx.x * 256 + threadIdx.x;       // (tg, s, lane)
  if (idx >= (WG_T0 + 2) * FT_S * 64) return;
  int lane = idx & 63;
  int rest = idx >> 6;
  int s  = rest % FT_S;
  int tg = rest / FT_S;
  int t0 = s * 16 + (lane >> 5) * 8;
  const float* W; int f; bool fval;
  if (tg < WG_T0) {
    int k = tg / FT_NIT, ft = tg % FT_NIT;
    f = ft * 32 + (lane & 31);
    W = fp.w1[k];
    fval = (f < F_DIM);
  } else {
    f = (tg - WG_T0) * 32 + (lane & 31);          // hidden unit 0..63
    W = wgW1;
    fval = true;
  }
  s16x8 o;
  #pragma unroll
  for (int j = 0; j < 8; ++j) {
    int t = t0 + j;
    o[j] = (fval && t < T_DIM) ? (short)f2bf(W[(size_t)f * T_DIM + t]) : (short)0;
  }
  *(s16x8*)&w1g[(size_t)idx * 8] = o;
}

// ---------------------------------------------------------------------------
// Kernel A: mu/sigma MLPs (fp32 register-tiled). Unchanged from round 2.
// ---------------------------------------------------------------------------
__global__ __launch_bounds__(256) void musig_kernel(
    const float* __restrict__ x,
    const float* __restrict__ muW1, const float* __restrict__ mub1,
    const float* __restrict__ muW2, const float* __restrict__ mub2,
    const float* __restrict__ sgW1, const float* __restrict__ sgb1,
    const float* __restrict__ sgW2, const float* __restrict__ sgb2,
    float* __restrict__ spmu, float* __restrict__ spsg)
{
  int r0 = blockIdx.x * 32;
  __shared__ __align__(16) float xt[T_DIM][32];
  __shared__ __align__(16) float w1t[24][128];
  __shared__ float h[32][132];
  __shared__ float w2s[8][66];
  int tid = threadIdx.x;

  {
    int r = tid & 31;
    const float* xp = x + (size_t)(r0 + r) * T_DIM;
    for (int c = (tid >> 5); c < 84; c += 8) {
      float4 v = ((const float4*)xp)[c];
      int t = c * 4;
      xt[t][r] = v.x; xt[t+1][r] = v.y; xt[t+2][r] = v.z; xt[t+3][r] = v.w;
    }
  }
  {
    int o = tid >> 5, j = tid & 31;
    w2s[o][j]      = (o < 4) ? muW2[o * 64 + j]      : sgW2[(o - 4) * 64 + j];
    w2s[o][j + 32] = (o < 4) ? muW2[o * 64 + j + 32] : sgW2[(o - 4) * 64 + j + 32];
  }

  int tr = tid & 7, tf = tid >> 3;
  float acc[4][4] = {};
  for (int t0 = 0; t0 < T_DIM; t0 += 24) {
    __syncthreads();
    {
      int ff = tid & 127;
      const float* Wr = (ff < 64) ? (muW1 + (size_t)ff * T_DIM)
                                  : (sgW1 + (size_t)(ff - 64) * T_DIM);
      for (int c2 = tid >> 7; c2 < 6; c2 += 2) {
        float4 v = ((const float4*)(Wr + t0))[c2];
        int tt = c2 * 4;
        w1t[tt][ff] = v.x; w1t[tt+1][ff] = v.y; w1t[tt+2][ff] = v.z; w1t[tt+3][ff] = v.w;
      }
    }
    __syncthreads();
    #pragma unroll
    for (int t = 0; t < 24; ++t) {
      float4 zv = *(const float4*)&xt[t0 + t][tr * 4];
      float4 wv = *(const float4*)&w1t[t][tf * 4];
      acc[0][0] = fmaf(zv.x, wv.x, acc[0][0]); acc[0][1] = fmaf(zv.x, wv.y, acc[0][1]);
      acc[0][2] = fmaf(zv.x, wv.z, acc[0][2]); acc[0][3] = fmaf(zv.x, wv.w, acc[0][3]);
      acc[1][0] = fmaf(zv.y, wv.x, acc[1][0]); acc[1][1] = fmaf(zv.y, wv.y, acc[1][1]);
      acc[1][2] = fmaf(zv.y, wv.z, acc[1][2]); acc[1][3] = fmaf(zv.y, wv.w, acc[1][3]);
      acc[2][0] = fmaf(zv.z, wv.x, acc[2][0]); acc[2][1] = fmaf(zv.z, wv.y, acc[2][1]);
      acc[2][2] = fmaf(zv.z, wv.z, acc[2][2]); acc[2][3] = fmaf(zv.z, wv.w, acc[2][3]);
      acc[3][0] = fmaf(zv.w, wv.x, acc[3][0]); acc[3][1] = fmaf(zv.w, wv.y, acc[3][1]);
      acc[3][2] = fmaf(zv.w, wv.z, acc[3][2]); acc[3][3] = fmaf(zv.w, wv.w, acc[3][3]);
    }
  }
  #pragma unroll
  for (int jr = 0; jr < 4; ++jr)
    #pragma unroll
    for (int jc = 0; jc < 4; ++jc) {
      int j = tf * 4 + jc;
      float b = (j < 64) ? mub1[j] : sgb1[j - 64];
      h[tr * 4 + jr][j] = fmaxf(acc[jr][jc] + b, 0.f);
    }
  __syncthreads();
  {
    int r = tid >> 3, o = tid & 7;
    const float* hb = &h[r][(o < 4) ? 0 : 64];
    float a = 0.f;
    #pragma unroll 16
    for (int j = 0; j < 64; ++j) a = fmaf(hb[j], w2s[o][j], a);
    a += (o < 4) ? mub2[o] : sgb2[o - 4];
    float sp = fmaxf(a, 0.f) + log1pf(expf(-fabsf(a)));
    if (o < 4) spmu[(size_t)(r0 + r) * 4 + o] = sp;
    else       spsg[(size_t)(r0 + r) * 4 + (o - 4)] = sp;
  }
}

// ---------------------------------------------------------------------------
// Kernel F: fused fitter + weight-gen, bf16 MFMA (32x32x16), fragment-order
// LDS, 2-phase prefetch.  Block: 128 rows x one k.  4 waves = 4 row-groups.
// Per f-half-tile (32 f): wave reads its A-frag + shared B-frag per K-step,
// 22 MFMA; epilogue fuses relu + W2 into 48 persistent register partials.
// Tiles 23,24 are the wg hidden layer -> logits (softmax done in combine).
// ---------------------------------------------------------------------------
__global__ __launch_bounds__(256, 1) void fitter_mfma_kernel(
    const float* __restrict__ eps, const float* __restrict__ spmu,
    const float* __restrict__ spsg, const unsigned short* __restrict__ w1g,
    FitParams fp, const float* __restrict__ wgb1, const float* __restrict__ wgW2,
    float* __restrict__ coeffs, float* __restrict__ logits)
{
  int k = blockIdx.y;
  int r0 = blockIdx.x * FT_BM;
  const float* B1 = fp.b1[k];
  const float* W2 = fp.w2[k];
  const float* B2 = fp.b2[k];
  int deg = (k == 1) ? 2 : (k == 2) ? 3 : 1;

  __shared__ __align__(16) unsigned short sZ[4 * TILE_SH];   // 90112 B
  __shared__ __align__(16) unsigned short sW[2][TILE_SH];    // 2 x 22528 B

  int tid = threadIdx.x;
  int lane = tid & 63;
  int rg = tid >> 6;          // wave id == row group (rows rg*32..+32)
  int l31 = lane & 31;

  // ---- stage Z once: fragment order.  thread: row = tid>>1, chunks c = (tid&1)+2j
  {
    int r = tid >> 1;
    float m = spmu[(size_t)(r0 + r) * 4 + k];
    float s = spsg[(size_t)(r0 + r) * 4 + k];
    const float* ep = eps + ((size_t)(r0 + r) * 4 + k) * T_DIM;
    int zrg = r >> 5;
    int ldest = (r & 31);
    #pragma unroll
    for (int c = (tid & 1); c < 44; c += 2) {
      s16x8 o = {0, 0, 0, 0, 0, 0, 0, 0};
      if (c < 42) {
        float4 e0 = ((const float4*)ep)[c * 2];
        float4 e1 = ((const float4*)ep)[c * 2 + 1];
        o[0] = (short)f2bf(fmaf(e0.x, s, m)); o[1] = (short)f2bf(fmaf(e0.y, s, m));
        o[2] = (short)f2bf(fmaf(e0.z, s, m)); o[3] = (short)f2bf(fmaf(e0.w, s, m));
        o[4] = (short)f2bf(fmaf(e1.x, s, m)); o[5] = (short)f2bf(fmaf(e1.y, s, m));
        o[6] = (short)f2bf(fmaf(e1.z, s, m)); o[7] = (short)f2bf(fmaf(e1.w, s, m));
      }
      int sstep = c >> 1, kh = c & 1;
      *(s16x8*)&sZ[(((size_t)zrg * FT_S + sstep) * 64 + ldest + 32 * kh) * 8] = o;
    }
  }

  // ---- prefetch W tile 0
  {
    const unsigned short* g = w1g + (size_t)(k * FT_NIT) * TILE_SH;
    for (int i = tid; i < FT_S * 64; i += 256)
      gl_lds16(g + (size_t)i * 8, &sW[0][(size_t)i * 8]);
  }
  __syncthreads();

  // persistent per-lane partials: 16 C-rows x {c0,c1,c2,logit}
  float cp0[16] = {}, cp1[16] = {}, cp2[16] = {}, lgp[16] = {};

  const s16x8* As = (const s16x8*)&sZ[((size_t)rg * FT_S * 64 + lane) * 8];

  for (int it = 0; it < FT_NIT + 2; ++it) {
    // issue prefetch of next tile into the other buffer
    int nt = it + 1;
    if (nt < FT_NIT + 2) {
      int tg = (nt < FT_NIT) ? (k * FT_NIT + nt) : (WG_T0 + (nt - FT_NIT));
      const unsigned short* g = w1g + (size_t)tg * TILE_SH;
      unsigned short* d = &sW[nt & 1][0];
      for (int i = tid; i < FT_S * 64; i += 256)
        gl_lds16(g + (size_t)i * 8, d + (size_t)i * 8);
    }

    // compute on current buffer
    const s16x8* Bs = (const s16x8*)&sW[it & 1][(size_t)lane * 8];
    f32x16 acc = {0.f, 0.f, 0.f, 0.f, 0.f, 0.f, 0.f, 0.f,
                  0.f, 0.f, 0.f, 0.f, 0.f, 0.f, 0.f, 0.f};
    #pragma unroll
    for (int s = 0; s < FT_S; ++s) {
      s16x8 a = As[s * 64];
      s16x8 b = Bs[s * 64];
      acc = __builtin_amdgcn_mfma_f32_32x32x16_bf16(a, b, acc, 0, 0, 0);
    }

    if (it < FT_NIT) {
      int f = it * 32 + l31;
      bool v = (f < F_DIM);
      float b1v = v ? B1[f] : 0.f;
      float w2a = v ? W2[f] : 0.f;
      float w2b = (v && deg > 1) ? W2[F_DIM + f] : 0.f;
      float w2c = (v && deg > 2) ? W2[2 * F_DIM + f] : 0.f;
      #pragma unroll
      for (int p = 0; p < 16; ++p) {
        float hv = fmaxf(acc[p] + b1v, 0.f);
        cp0[p] = fmaf(hv, w2a, cp0[p]);
        cp1[p] = fmaf(hv, w2b, cp1[p]);
        cp2[p] = fmaf(hv, w2c, cp2[p]);
      }
    } else {
      int h = (it - FT_NIT) * 32 + l31;
      float b1v = wgb1[h];
      float w2v = wgW2[h];
      #pragma unroll
      for (int p = 0; p < 16; ++p) {
        float hv = fmaxf(acc[p] + b1v, 0.f);
        lgp[p] = fmaf(hv, w2v, lgp[p]);
      }
    }
    __syncthreads();   // drains prefetch vmcnt + protects buffer swap
  }

  // ---- reduce over the 32 f-lanes; lanes 0 and 32 own 16 disjoint rows each
  float bb0 = B2[0];
  float bb1 = (deg > 1) ? B2[1] : 0.f;
  float bb2 = (deg > 2) ? B2[2] : 0.f;
  #pragma unroll
  for (int p = 0; p < 16; ++p) {
    float a0 = cp0[p], a1 = cp1[p], a2 = cp2[p], a3 = lgp[p];
    #pragma unroll
    for (int m = 1; m <= 16; m <<= 1) {
      a0 += __shfl_xor(a0, m); a1 += __shfl_xor(a1, m);
      a2 += __shfl_xor(a2, m); a3 += __shfl_xor(a3, m);
    }
    if (l31 == 0) {
      int row = r0 + rg * 32 + (p & 3) + 8 * (p >> 2) + 4 * (lane >> 5);
      float* cr = coeffs + (size_t)row * 12 + k * 3;
      cr[0] = a0 + bb0;
      cr[1] = a1 + bb1;
      cr[2] = a2 + bb2;
      logits[(size_t)row * 4 + k] = a3;
    }
  }
}

// ---------------------------------------------------------------------------
// Kernel C: softmax over logits + combine coeffs into cubic, evaluate at
// t_f = f/719, write out[b][f][n] coalesced over n.
// ---------------------------------------------------------------------------
__global__ __launch_bounds__(256) void combine_kernel(
    const float* __restrict__ coeffs, const float* __restrict__ logits,
    float* __restrict__ out)
{
  int b = blockIdx.x;
  int fc = blockIdx.y;
  __shared__ float P[4][128];
  int tid = threadIdx.x;
  if (tid < 128) {
    size_t bn = (size_t)b * 128 + tid;
    const float* lg = logits + bn * 4;
    float l0 = lg[0], l1 = lg[1], l2 = lg[2], l3 = lg[3];
    float m = fmaxf(fmaxf(l0, l1), fmaxf(l2, l3));
    float e0 = expf(l0 - m), e1 = expf(l1 - m);
    float e2 = expf(l2 - m), e3 = expf(l3 - m);
    float inv = 1.f / (e0 + e1 + e2 + e3);
    float w0 = e0 * inv, w1 = e1 * inv, w2 = e2 * inv, w3 = e3 * inv;
    const float* c = coeffs + bn * 12;
    // degrees [1,2,3,1], signs [+.5,+.5,+.5,-.5]
    P[0][tid] = w0 * c[0] + w1 * c[3] + w2 * c[6] + w3 * c[9];
    P[1][tid] = w1 * c[4] + w2 * c[7] + 0.5f * (w0 - w3);
    P[2][tid] = w2 * c[8] + 0.5f * w1;
    P[3][tid] = 0.5f * w2;
  }
  __syncthreads();
  int n = tid & 127, fo = tid >> 7;
  float p0 = P[0][n], p1 = P[1][n], p2 = P[2][n], p3 = P[3][n];
  float* ob = out + (size_t)b * F_DIM * 128 + n;
  for (int f = fc * 120 + fo; f < fc * 120 + 120; f += 2) {
    float t = (float)f * (1.0f / 719.0f);
    ob[(size_t)f * 128] = fmaf(fmaf(fmaf(p3, t, p2), t, p1), t, p0);
  }
}

// ---------------------------------------------------------------------------
extern "C" void kernel_launch(void* const* d_in, const int* in_sizes, int n_in,
                              void* d_out, int out_size, void* d_ws, size_t ws_size,
                              hipStream_t stream) {
  const float* x    = (const float*)d_in[0];
  const float* eps  = (const float*)d_in[1];
  const float* muW1 = (const float*)d_in[2];
  const float* mub1 = (const float*)d_in[3];
  const float* muW2 = (const float*)d_in[4];
  const float* mub2 = (const float*)d_in[5];
  const float* sgW1 = (const float*)d_in[6];
  const float* sgb1 = (const float*)d_in[7];
  const float* sgW2 = (const float*)d_in[8];
  const float* sgb2 = (const float*)d_in[9];
  const float* wgW1 = (const float*)d_in[10];
  const float* wgb1 = (const float*)d_in[11];
  const float* wgW2 = (const float*)d_in[12];
  // wgb2 (d_in[13]) dropped: softmax is invariant to a shared logit offset.

  float* ws     = (float*)d_ws;
  float* spmu   = ws;                              // 65536 f
  float* spsg   = ws + 65536;                      // 65536 f
  float* logits = ws + 131072;                     // 65536 f
  float* coeffs = ws + 196608;                     // 196608 f
  unsigned short* w1g = (unsigned short*)(ws + 393216);  // 94 tiles * 22528 B

  FitParams fp;
  for (int i = 0; i < 4; ++i) {
    fp.w1[i] = (const float*)d_in[14 + 4 * i];
    fp.b1[i] = (const float*)d_in[15 + 4 * i];
    fp.w2[i] = (const float*)d_in[16 + 4 * i];
    fp.b2[i] = (const float*)d_in[17 + 4 * i];
  }

  int wconv_threads = (WG_T0 + 2) * FT_S * 64;
  wconv_kernel<<<(wconv_threads + 255) / 256, 256, 0, stream>>>(fp, wgW1, w1g);
  musig_kernel<<<BN_TOT / 32, 256, 0, stream>>>(
      x, muW1, mub1, muW2, mub2, sgW1, sgb1, sgW2, sgb2, spmu, spsg);
  fitter_mfma_kernel<<<dim3(BN_TOT / FT_BM, 4), 256, 0, stream>>>(
      eps, spmu, spsg, w1g, fp, wgb1, wgW2, coeffs, logits);
  combine_kernel<<<dim3(128, 6), 256, 0, stream>>>(coeffs, logits, (float*)d_out);
}